// Round 1
// baseline (793.340 us; speedup 1.0000x reference)
//
#include <hip/hip_runtime.h>

// ---------------- problem constants ----------------
#define N_NODES 100000
#define N_EDGES 1600000
#define DIM     128      // IN_DIM == HIDDEN
#define OUTD    16
#define SCAN_CHUNK 1024
#define NB ((N_NODES + SCAN_CHUNK - 1) / SCAN_CHUNK)   // 98 scan blocks

static __device__ __forceinline__ float frelu(float v) { return v > 0.f ? v : 0.f; }

// ---------------- degree count ----------------
__global__ void k_count(const int* __restrict__ row, int* __restrict__ deg) {
    int stride = gridDim.x * blockDim.x;
    for (int e = blockIdx.x * blockDim.x + threadIdx.x; e < N_EDGES; e += stride)
        atomicAdd(&deg[row[e]], 1);
}

// ---------------- scan pass 1: per-block sums ----------------
__global__ void k_scan1(const int* __restrict__ deg, int* __restrict__ bsum) {
    __shared__ int sd[256];
    int t = threadIdx.x;
    int base = blockIdx.x * SCAN_CHUNK + t * 4;
    int s = 0;
#pragma unroll
    for (int j = 0; j < 4; ++j) {
        int i = base + j;
        if (i < N_NODES) s += deg[i];
    }
    sd[t] = s;
    __syncthreads();
    for (int off = 128; off > 0; off >>= 1) {
        if (t < off) sd[t] += sd[t + off];
        __syncthreads();
    }
    if (t == 0) bsum[blockIdx.x] = sd[0];
}

// ---------------- scan pass 2: scan of block sums (tiny) ----------------
__global__ void k_scan2(const int* __restrict__ bsum, int* __restrict__ boff,
                        int* __restrict__ offsets) {
    if (threadIdx.x == 0 && blockIdx.x == 0) {
        int run = 0;
        for (int i = 0; i < NB; ++i) { boff[i] = run; run += bsum[i]; }
        offsets[N_NODES] = run;   // == N_EDGES
    }
}

// ---------------- scan pass 3: write exclusive offsets + cursor ----------------
__global__ void k_scan3(const int* __restrict__ deg, const int* __restrict__ boff,
                        int* __restrict__ offsets, int* __restrict__ cursor) {
    __shared__ int sd[256];
    int t = threadIdx.x;
    int base = blockIdx.x * SCAN_CHUNK + t * 4;
    int d[4];
    int s = 0;
#pragma unroll
    for (int j = 0; j < 4; ++j) {
        int i = base + j;
        d[j] = (i < N_NODES) ? deg[i] : 0;
        s += d[j];
    }
    sd[t] = s;
    __syncthreads();
    // inclusive Hillis-Steele over 256 thread sums
    for (int off = 1; off < 256; off <<= 1) {
        int add = (t >= off) ? sd[t - off] : 0;
        __syncthreads();
        sd[t] += add;
        __syncthreads();
    }
    int run = boff[blockIdx.x] + (sd[t] - s);   // exclusive prefix for this thread
#pragma unroll
    for (int j = 0; j < 4; ++j) {
        int i = base + j;
        if (i < N_NODES) {
            offsets[i] = run;
            cursor[i]  = run;
            run += d[j];
        }
    }
}

// ---------------- scatter edges into CSR buckets ----------------
__global__ void k_scatter(const int* __restrict__ row, const int* __restrict__ col,
                          int* __restrict__ cursor, int* __restrict__ csr_col) {
    int stride = gridDim.x * blockDim.x;
    for (int e = blockIdx.x * blockDim.x + threadIdx.x; e < N_EDGES; e += stride) {
        int r = row[e];
        int p = atomicAdd(&cursor[r], 1);
        csr_col[p] = col[e];
    }
}

// ---------------- SpMM: out[i] = sum_{j in N(i)} in[j], one wave per node ----------------
__global__ __launch_bounds__(256) void k_spmm(const float* __restrict__ in,
                                              float* __restrict__ out,
                                              const int* __restrict__ offsets,
                                              const int* __restrict__ csr_col) {
    int wid  = threadIdx.x >> 6;
    int lane = threadIdx.x & 63;
    int node = blockIdx.x * 4 + wid;
    if (node >= N_NODES) return;
    int start = offsets[node];
    int end   = offsets[node + 1];
    float ax = 0.f, ay = 0.f;
    for (int base = start; base < end; base += 64) {
        int idx = 0;
        if (base + lane < end) idx = csr_col[base + lane];
        int cnt = min(64, end - base);
        for (int j = 0; j < cnt; ++j) {
            int c = __shfl(idx, j, 64);
            float2 v = *(const float2*)(in + (size_t)c * DIM + lane * 2);
            ax += v.x;
            ay += v.y;
        }
    }
    float2 r; r.x = ax; r.y = ay;
    *(float2*)(out + (size_t)node * DIM + lane * 2) = r;
}

// ---------------- fused 3-branch GEMM + relu + classifier ----------------
#define TN 32
#define HS_STRIDE 388   // 384 used + pad to keep float4 alignment & spread banks

__global__ __launch_bounds__(256) void k_fused(
        const float* __restrict__ x, const float* __restrict__ y1,
        const float* __restrict__ y2, const int* __restrict__ deg,
        const float* __restrict__ W_ego, const float* __restrict__ b_ego,
        const float* __restrict__ W_h1,  const float* __restrict__ b_h1,
        const float* __restrict__ W_h2,  const float* __restrict__ b_h2,
        const float* __restrict__ W_cls, const float* __restrict__ b_cls,
        float* __restrict__ out) {
    __shared__ __align__(16) float Xs[TN * DIM];        // 16 KB staged input tile
    __shared__ __align__(16) float Hs[TN * HS_STRIDE];  // ~49.7 KB hidden concat

    int t = threadIdx.x;
    int node0 = blockIdx.x * TN;
    int h    = (t & 63) * 2;   // hidden pair this thread owns
    int ngrp = t >> 6;         // node group 0..3 (8 nodes each)

    for (int br = 0; br < 3; ++br) {
        const float* src  = (br == 0) ? x     : (br == 1) ? y1   : y2;
        const float* W    = (br == 0) ? W_ego : (br == 1) ? W_h1 : W_h2;
        const float* bias = (br == 0) ? b_ego : (br == 1) ? b_h1 : b_h2;

        __syncthreads();   // protect Xs reuse across branches
        // stage [TN x DIM] tile (contiguous rows) with degree normalization
        for (int idx = t * 4; idx < TN * DIM; idx += 256 * 4) {
            float4 v = *(const float4*)(src + (size_t)node0 * DIM + idx);
            if (br > 0) {
                int n  = idx >> 7;            // node within tile
                int dg = deg[node0 + n];
                float dv = 1.0f / (float)max(dg, 1);
                float sc = (br == 1) ? dv : dv * dv;
                v.x *= sc; v.y *= sc; v.z *= sc; v.w *= sc;
            }
            *(float4*)(Xs + idx) = v;
        }
        __syncthreads();

        float2 acc[8];
#pragma unroll
        for (int n = 0; n < 8; ++n) { acc[n].x = 0.f; acc[n].y = 0.f; }

        const float* xrow = Xs + (ngrp * 8) * DIM;
        for (int k0 = 0; k0 < DIM; k0 += 4) {
            float2 w0 = *(const float2*)(W + (size_t)(k0 + 0) * DIM + h);
            float2 w1 = *(const float2*)(W + (size_t)(k0 + 1) * DIM + h);
            float2 w2 = *(const float2*)(W + (size_t)(k0 + 2) * DIM + h);
            float2 w3 = *(const float2*)(W + (size_t)(k0 + 3) * DIM + h);
#pragma unroll
            for (int n = 0; n < 8; ++n) {
                float4 xv = *(const float4*)(xrow + n * DIM + k0);
                acc[n].x += xv.x * w0.x; acc[n].y += xv.x * w0.y;
                acc[n].x += xv.y * w1.x; acc[n].y += xv.y * w1.y;
                acc[n].x += xv.z * w2.x; acc[n].y += xv.z * w2.y;
                acc[n].x += xv.w * w3.x; acc[n].y += xv.w * w3.y;
            }
        }

        float2 bb = *(const float2*)(bias + h);
#pragma unroll
        for (int n = 0; n < 8; ++n) {
            int nn = ngrp * 8 + n;
            Hs[nn * HS_STRIDE + br * DIM + h]     = frelu(acc[n].x + bb.x);
            Hs[nn * HS_STRIDE + br * DIM + h + 1] = frelu(acc[n].y + bb.y);
        }
    }
    __syncthreads();

    // classifier: 32 nodes x 16 outputs; each thread does 2 (node, out) pairs
    int o  = t & 15;
    int nn = t >> 4;   // 0..15
    const float4* h0 = (const float4*)(Hs + nn * HS_STRIDE);
    const float4* h1 = (const float4*)(Hs + (nn + 16) * HS_STRIDE);
    float a0 = 0.f, a1 = 0.f;
    for (int u4 = 0; u4 < 96; ++u4) {
        float4 v0 = h0[u4];
        float4 v1 = h1[u4];
        float w0 = W_cls[(size_t)(u4 * 4 + 0) * OUTD + o];
        float w1 = W_cls[(size_t)(u4 * 4 + 1) * OUTD + o];
        float w2 = W_cls[(size_t)(u4 * 4 + 2) * OUTD + o];
        float w3 = W_cls[(size_t)(u4 * 4 + 3) * OUTD + o];
        a0 += v0.x * w0 + v0.y * w1 + v0.z * w2 + v0.w * w3;
        a1 += v1.x * w0 + v1.y * w1 + v1.z * w2 + v1.w * w3;
    }
    float bc = b_cls[o];
    out[(size_t)(node0 + nn) * OUTD + o]      = a0 + bc;
    out[(size_t)(node0 + nn + 16) * OUTD + o] = a1 + bc;
}

// ---------------- launcher ----------------
static inline size_t align256(size_t v) { return (v + 255) & ~(size_t)255; }

extern "C" void kernel_launch(void* const* d_in, const int* in_sizes, int n_in,
                              void* d_out, int out_size, void* d_ws, size_t ws_size,
                              hipStream_t stream) {
    const float* x      = (const float*)d_in[0];
    const int*   ei     = (const int*)d_in[1];     // [2][E] int32
    const float* W_ego  = (const float*)d_in[2];
    const float* b_ego  = (const float*)d_in[3];
    const float* W_h1   = (const float*)d_in[4];
    const float* b_h1   = (const float*)d_in[5];
    const float* W_h2   = (const float*)d_in[6];
    const float* b_h2   = (const float*)d_in[7];
    const float* W_cls  = (const float*)d_in[8];
    const float* b_cls  = (const float*)d_in[9];
    float* out = (float*)d_out;

    const int* row = ei;
    const int* col = ei + N_EDGES;

    // workspace partition (~110 MB)
    char* p = (char*)d_ws;
    int* deg     = (int*)p; p += align256((size_t)N_NODES * 4);
    int* offsets = (int*)p; p += align256((size_t)(N_NODES + 1) * 4);
    int* cursor  = (int*)p; p += align256((size_t)N_NODES * 4);
    int* bsum    = (int*)p; p += align256((size_t)NB * 4);
    int* boff    = (int*)p; p += align256((size_t)NB * 4);
    int* csr_col = (int*)p; p += align256((size_t)N_EDGES * 4);
    float* y1    = (float*)p; p += align256((size_t)N_NODES * DIM * 4);
    float* y2    = (float*)p; p += align256((size_t)N_NODES * DIM * 4);

    hipMemsetAsync(deg, 0, (size_t)N_NODES * 4, stream);

    k_count<<<1024, 256, 0, stream>>>(row, deg);
    k_scan1<<<NB, 256, 0, stream>>>(deg, bsum);
    k_scan2<<<1, 64, 0, stream>>>(bsum, boff, offsets);
    k_scan3<<<NB, 256, 0, stream>>>(deg, boff, offsets, cursor);
    k_scatter<<<1024, 256, 0, stream>>>(row, col, cursor, csr_col);

    k_spmm<<<(N_NODES + 3) / 4, 256, 0, stream>>>(x,  y1, offsets, csr_col);
    k_spmm<<<(N_NODES + 3) / 4, 256, 0, stream>>>(y1, y2, offsets, csr_col);

    k_fused<<<N_NODES / TN, 256, 0, stream>>>(x, y1, y2, deg,
                                              W_ego, b_ego, W_h1, b_h1,
                                              W_h2, b_h2, W_cls, b_cls, out);
}

// Round 2
// 486.178 us; speedup vs baseline: 1.6318x; 1.6318x over previous
//
#include <hip/hip_runtime.h>

#define N_NODES 100000
#define N_EDGES 1600000
#define DIM     128
#define OUTD    16
#define SCAN_CHUNK 1024
#define NB ((N_NODES + SCAN_CHUNK - 1) / SCAN_CHUNK)   // 98

typedef unsigned int  uint;
typedef unsigned short ushort;
typedef __attribute__((ext_vector_type(8))) short short8;   // 8 bf16 (4 VGPRs)
typedef __attribute__((ext_vector_type(4))) float f32x4;    // MFMA C/D

__device__ __forceinline__ ushort f2bf(float f) {           // RNE fp32->bf16
    uint u = __float_as_uint(f);
    u = u + 0x7fffu + ((u >> 16) & 1u);
    return (ushort)(u >> 16);
}
__device__ __forceinline__ float bflo(uint v) { return __uint_as_float(v << 16); }
__device__ __forceinline__ float bfhi(uint v) { return __uint_as_float(v & 0xffff0000u); }

// ---------------- prep: degree count + x->bf16 + W transposes->bf16 ----------------
__global__ __launch_bounds__(256) void k_prep(
        const float4* __restrict__ x4, const int* __restrict__ row,
        const float* __restrict__ We, const float* __restrict__ W1,
        const float* __restrict__ W2, const float* __restrict__ Wc,
        ushort* __restrict__ xb, ushort* __restrict__ Wt, ushort* __restrict__ Wct,
        int* __restrict__ deg) {
    int tid = blockIdx.x * blockDim.x + threadIdx.x;
    int stride = gridDim.x * blockDim.x;
    for (int e = tid; e < N_EDGES; e += stride) atomicAdd(&deg[row[e]], 1);
    for (int i = tid; i < N_NODES * DIM / 4; i += stride) {
        float4 v = x4[i];
        ushort4 r;
        r.x = f2bf(v.x); r.y = f2bf(v.y); r.z = f2bf(v.z); r.w = f2bf(v.w);
        *(ushort4*)(xb + (size_t)i * 4) = r;
    }
    for (int i = tid; i < 3 * DIM * DIM; i += stride) {   // Wt[br][n][k] = W[br][k][n]
        int b = i >> 14, r2 = i & (DIM * DIM - 1);
        int k = r2 >> 7, n = r2 & 127;
        const float* W = (b == 0) ? We : (b == 1) ? W1 : W2;
        Wt[b * DIM * DIM + n * DIM + k] = f2bf(W[r2]);
    }
    for (int i = tid; i < 384 * OUTD; i += stride) {      // Wct[o][k] = Wc[k][o]
        int k = i >> 4, o = i & 15;
        Wct[o * 384 + k] = f2bf(Wc[i]);
    }
}

// ---------------- scans (build CSR offsets) ----------------
__global__ void k_scan1(const int* __restrict__ deg, int* __restrict__ bsum) {
    __shared__ int sd[256];
    int t = threadIdx.x;
    int base = blockIdx.x * SCAN_CHUNK + t * 4;
    int s = 0;
#pragma unroll
    for (int j = 0; j < 4; ++j) { int i = base + j; if (i < N_NODES) s += deg[i]; }
    sd[t] = s;
    __syncthreads();
    for (int off = 128; off > 0; off >>= 1) {
        if (t < off) sd[t] += sd[t + off];
        __syncthreads();
    }
    if (t == 0) bsum[blockIdx.x] = sd[0];
}

__global__ void k_scan2(const int* __restrict__ bsum, int* __restrict__ boff,
                        int* __restrict__ offsets) {
    __shared__ int s[128];
    int t = threadIdx.x;
    int v = (t < NB) ? bsum[t] : 0;
    s[t] = v;
    __syncthreads();
    for (int off = 1; off < 128; off <<= 1) {
        int a = (t >= off) ? s[t - off] : 0;
        __syncthreads();
        s[t] += a;
        __syncthreads();
    }
    if (t < NB) boff[t] = s[t] - v;
    if (t == NB - 1) offsets[N_NODES] = s[t];
}

__global__ void k_scan3(const int* __restrict__ deg, const int* __restrict__ boff,
                        int* __restrict__ offsets, int* __restrict__ cursor) {
    __shared__ int sd[256];
    int t = threadIdx.x;
    int base = blockIdx.x * SCAN_CHUNK + t * 4;
    int d[4];
    int s = 0;
#pragma unroll
    for (int j = 0; j < 4; ++j) {
        int i = base + j;
        d[j] = (i < N_NODES) ? deg[i] : 0;
        s += d[j];
    }
    sd[t] = s;
    __syncthreads();
    for (int off = 1; off < 256; off <<= 1) {
        int add = (t >= off) ? sd[t - off] : 0;
        __syncthreads();
        sd[t] += add;
        __syncthreads();
    }
    int run = boff[blockIdx.x] + (sd[t] - s);
#pragma unroll
    for (int j = 0; j < 4; ++j) {
        int i = base + j;
        if (i < N_NODES) { offsets[i] = run; cursor[i] = run; run += d[j]; }
    }
}

__global__ void k_scatter(const int* __restrict__ row, const int* __restrict__ col,
                          int* __restrict__ cursor, int* __restrict__ csr_col) {
    int stride = gridDim.x * blockDim.x;
    for (int e = blockIdx.x * blockDim.x + threadIdx.x; e < N_EDGES; e += stride) {
        int p = atomicAdd(&cursor[row[e]], 1);
        csr_col[p] = col[e];
    }
}

// ---------------- SpMM (bf16 in/out, fp32 accum), one wave per node ----------------
// MODE 1: out = (sum x[c]) * dinv[node]
// MODE 2: out = (sum x[c]*max(deg[c],1)) * dinv[node]^2   (input rows pre-normalized)
template <int MODE>
__global__ __launch_bounds__(256) void k_spmm(const ushort* __restrict__ in,
                                              ushort* __restrict__ outp,
                                              const int* __restrict__ offsets,
                                              const int* __restrict__ csr_col,
                                              const int* __restrict__ deg) {
    int wid = threadIdx.x >> 6, lane = threadIdx.x & 63;
    int node = blockIdx.x * 4 + wid;
    int start = __builtin_amdgcn_readfirstlane(offsets[node]);
    int end   = __builtin_amdgcn_readfirstlane(offsets[node + 1]);
    float a0 = 0.f, a1 = 0.f;
    int j = start;
    for (; j + 4 <= end; j += 4) {
        int c0 = csr_col[j + 0], c1 = csr_col[j + 1];
        int c2 = csr_col[j + 2], c3 = csr_col[j + 3];
        uint v0 = *(const uint*)(in + ((size_t)c0 << 7) + lane * 2);
        uint v1 = *(const uint*)(in + ((size_t)c1 << 7) + lane * 2);
        uint v2 = *(const uint*)(in + ((size_t)c2 << 7) + lane * 2);
        uint v3 = *(const uint*)(in + ((size_t)c3 << 7) + lane * 2);
        if (MODE == 2) {
            float s0 = (float)max(deg[c0], 1), s1 = (float)max(deg[c1], 1);
            float s2 = (float)max(deg[c2], 1), s3 = (float)max(deg[c3], 1);
            a0 += bflo(v0) * s0 + bflo(v1) * s1 + bflo(v2) * s2 + bflo(v3) * s3;
            a1 += bfhi(v0) * s0 + bfhi(v1) * s1 + bfhi(v2) * s2 + bfhi(v3) * s3;
        } else {
            a0 += bflo(v0) + bflo(v1) + bflo(v2) + bflo(v3);
            a1 += bfhi(v0) + bfhi(v1) + bfhi(v2) + bfhi(v3);
        }
    }
    for (; j < end; ++j) {
        int c = csr_col[j];
        uint v = *(const uint*)(in + ((size_t)c << 7) + lane * 2);
        float s = (MODE == 2) ? (float)max(deg[c], 1) : 1.f;
        a0 += bflo(v) * s;
        a1 += bfhi(v) * s;
    }
    float dv = 1.f / (float)max(deg[node], 1);
    float sc = (MODE == 2) ? dv * dv : dv;
    a0 *= sc; a1 *= sc;
    uint o = (uint)f2bf(a0) | ((uint)f2bf(a1) << 16);
    *(uint*)(outp + ((size_t)node << 7) + lane * 2) = o;
}

// ---------------- fused MFMA GEMM x3 + relu + classifier ----------------
#define XSS (DIM + 8)   // 136 bf16 = 272B row stride (2-way bank aliasing = free)

__global__ __launch_bounds__(256) void k_fused(
        const ushort* __restrict__ xb, const ushort* __restrict__ y1b,
        const ushort* __restrict__ y2b,
        const ushort* __restrict__ Wt, const ushort* __restrict__ Wct,
        const float* __restrict__ b_ego, const float* __restrict__ b_h1,
        const float* __restrict__ b_h2, const float* __restrict__ b_cls,
        float* __restrict__ out) {
    __shared__ __align__(16) ushort Xs[32 * XSS];   // 8704 B (also reduce buf)
    __shared__ __align__(16) ushort Hs[32 * XSS];   // 8704 B

    int t = threadIdx.x;
    int lane = t & 63, w = t >> 6;
    int q = lane >> 4, l = lane & 15;
    int node0 = blockIdx.x * 32;

    f32x4 cout0 = {0.f, 0.f, 0.f, 0.f}, cout1 = {0.f, 0.f, 0.f, 0.f};

    for (int br = 0; br < 3; ++br) {
        const ushort* src = (br == 0) ? xb : (br == 1) ? y1b : y2b;
        const ushort* Wtb = Wt + br * DIM * DIM;
        const float* bias = (br == 0) ? b_ego : (br == 1) ? b_h1 : b_h2;

        __syncthreads();   // prev-branch Xs/Hs readers done
        {   // stage 32x128 bf16 tile (pure copy; norm pre-folded in spmm)
            int row = t >> 3, col = (t & 7) * 16;
            const ushort* sp = src + ((size_t)(node0 + row) << 7) + col;
            uint4 u0 = *(const uint4*)sp;
            uint4 u1 = *(const uint4*)(sp + 8);
            *(uint4*)(Xs + row * XSS + col) = u0;
            *(uint4*)(Xs + row * XSS + col + 8) = u1;
        }
        __syncthreads();

        // A frags: A[m=l][k=ks*32+q*8+j] from Xs (row-major, k contiguous)
        short8 afr[2][4];
#pragma unroll
        for (int mt = 0; mt < 2; ++mt)
#pragma unroll
            for (int ks = 0; ks < 4; ++ks)
                afr[mt][ks] = *(const short8*)(Xs + (mt * 16 + l) * XSS + ks * 32 + q * 8);
        // B frags: B[k][n=l] == Wt[n][k] (k contiguous) -> one 16B global load each
        short8 bfr[2][4];
#pragma unroll
        for (int nt = 0; nt < 2; ++nt)
#pragma unroll
            for (int ks = 0; ks < 4; ++ks)
                bfr[nt][ks] = *(const short8*)(Wtb + (size_t)(w * 32 + nt * 16 + l) * DIM + ks * 32 + q * 8);

        f32x4 hc[2][2];
        hc[0][0] = hc[0][1] = hc[1][0] = hc[1][1] = (f32x4){0.f, 0.f, 0.f, 0.f};
#pragma unroll
        for (int ks = 0; ks < 4; ++ks)
#pragma unroll
            for (int mt = 0; mt < 2; ++mt)
#pragma unroll
                for (int nt = 0; nt < 2; ++nt)
                    hc[mt][nt] = __builtin_amdgcn_mfma_f32_16x16x32_bf16(
                        afr[mt][ks], bfr[nt][ks], hc[mt][nt], 0, 0, 0);

        // bias + relu -> Hs (bf16), C layout: row=q*4+r, col=l
#pragma unroll
        for (int nt = 0; nt < 2; ++nt) {
            float bv = bias[w * 32 + nt * 16 + l];
#pragma unroll
            for (int mt = 0; mt < 2; ++mt)
#pragma unroll
                for (int r = 0; r < 4; ++r) {
                    float v = hc[mt][nt][r] + bv;
                    v = v > 0.f ? v : 0.f;
                    Hs[(mt * 16 + q * 4 + r) * XSS + w * 32 + nt * 16 + l] = f2bf(v);
                }
        }
        __syncthreads();

        // classifier partial: this wave's K-slice [w*32, w*32+32)
        short8 ha0 = *(const short8*)(Hs + l * XSS + w * 32 + q * 8);
        short8 ha1 = *(const short8*)(Hs + (16 + l) * XSS + w * 32 + q * 8);
        short8 wc  = *(const short8*)(Wct + (size_t)l * 384 + br * DIM + w * 32 + q * 8);
        cout0 = __builtin_amdgcn_mfma_f32_16x16x32_bf16(ha0, wc, cout0, 0, 0, 0);
        cout1 = __builtin_amdgcn_mfma_f32_16x16x32_bf16(ha1, wc, cout1, 0, 0, 0);
    }

    // cross-wave reduce (reuse Xs as fp32 buffer [4][32][16])
    float* red = (float*)Xs;
#pragma unroll
    for (int r = 0; r < 4; ++r) {
        red[w * 512 + (q * 4 + r) * 16 + l]        = cout0[r];
        red[w * 512 + (16 + q * 4 + r) * 16 + l]   = cout1[r];
    }
    __syncthreads();
#pragma unroll
    for (int p = t; p < 512; p += 256) {
        float s = red[p] + red[512 + p] + red[1024 + p] + red[1536 + p];
        out[(size_t)node0 * OUTD + p] = s + b_cls[p & 15];
    }
}

// ---------------- launcher ----------------
static inline size_t align256(size_t v) { return (v + 255) & ~(size_t)255; }

extern "C" void kernel_launch(void* const* d_in, const int* in_sizes, int n_in,
                              void* d_out, int out_size, void* d_ws, size_t ws_size,
                              hipStream_t stream) {
    const float* x      = (const float*)d_in[0];
    const int*   ei     = (const int*)d_in[1];
    const float* W_ego  = (const float*)d_in[2];
    const float* b_ego  = (const float*)d_in[3];
    const float* W_h1   = (const float*)d_in[4];
    const float* b_h1   = (const float*)d_in[5];
    const float* W_h2   = (const float*)d_in[6];
    const float* b_h2   = (const float*)d_in[7];
    const float* W_cls  = (const float*)d_in[8];
    const float* b_cls  = (const float*)d_in[9];
    float* out = (float*)d_out;

    const int* row = ei;
    const int* col = ei + N_EDGES;

    char* p = (char*)d_ws;
    int* deg      = (int*)p;    p += align256((size_t)N_NODES * 4);
    int* offsets  = (int*)p;    p += align256((size_t)(N_NODES + 1) * 4);
    int* cursor   = (int*)p;    p += align256((size_t)N_NODES * 4);
    int* bsum     = (int*)p;    p += align256((size_t)NB * 4);
    int* boff     = (int*)p;    p += align256((size_t)NB * 4);
    int* csr_col  = (int*)p;    p += align256((size_t)N_EDGES * 4);
    ushort* xb    = (ushort*)p; p += align256((size_t)N_NODES * DIM * 2);
    ushort* y1b   = (ushort*)p; p += align256((size_t)N_NODES * DIM * 2);
    ushort* y2b   = (ushort*)p; p += align256((size_t)N_NODES * DIM * 2);
    ushort* Wt    = (ushort*)p; p += align256((size_t)3 * DIM * DIM * 2);
    ushort* Wct   = (ushort*)p; p += align256((size_t)384 * OUTD * 2);

    hipMemsetAsync(deg, 0, (size_t)N_NODES * 4, stream);

    k_prep<<<2048, 256, 0, stream>>>((const float4*)x, row, W_ego, W_h1, W_h2, W_cls,
                                     xb, Wt, Wct, deg);
    k_scan1<<<NB, 256, 0, stream>>>(deg, bsum);
    k_scan2<<<1, 128, 0, stream>>>(bsum, boff, offsets);
    k_scan3<<<NB, 256, 0, stream>>>(deg, boff, offsets, cursor);
    k_scatter<<<1024, 256, 0, stream>>>(row, col, cursor, csr_col);

    k_spmm<1><<<N_NODES / 4, 256, 0, stream>>>(xb,  y1b, offsets, csr_col, deg);
    k_spmm<2><<<N_NODES / 4, 256, 0, stream>>>(y1b, y2b, offsets, csr_col, deg);

    k_fused<<<N_NODES / 32, 256, 0, stream>>>(xb, y1b, y2b, Wt, Wct,
                                              b_ego, b_h1, b_h2, b_cls, out);
}

// Round 3
// 413.195 us; speedup vs baseline: 1.9200x; 1.1766x over previous
//
#include <hip/hip_runtime.h>

#define N_NODES 100000
#define N_EDGES 1600000
#define DIM     128
#define OUTD    16
#define SCAN_CHUNK 1024
#define NB ((N_NODES + SCAN_CHUNK - 1) / SCAN_CHUNK)   // 98

typedef unsigned int  uint;
typedef unsigned short ushort;
typedef __attribute__((ext_vector_type(8))) short short8;   // 8 bf16 (4 VGPRs)
typedef __attribute__((ext_vector_type(4))) float f32x4;    // MFMA C/D

__device__ __forceinline__ ushort f2bf(float f) {           // RNE fp32->bf16
    uint u = __float_as_uint(f);
    u = u + 0x7fffu + ((u >> 16) & 1u);
    return (ushort)(u >> 16);
}
__device__ __forceinline__ float bflo(uint v) { return __uint_as_float(v << 16); }
__device__ __forceinline__ float bfhi(uint v) { return __uint_as_float(v & 0xffff0000u); }

// ---------------- prep: degree count + x->bf16 + W transposes->bf16 ----------------
__global__ __launch_bounds__(256) void k_prep(
        const float4* __restrict__ x4, const int* __restrict__ row,
        const float* __restrict__ We, const float* __restrict__ W1,
        const float* __restrict__ W2, const float* __restrict__ Wc,
        ushort* __restrict__ xb, ushort* __restrict__ Wt, ushort* __restrict__ Wct,
        int* __restrict__ deg) {
    int tid = blockIdx.x * blockDim.x + threadIdx.x;
    int stride = gridDim.x * blockDim.x;
    for (int e = tid; e < N_EDGES; e += stride) atomicAdd(&deg[row[e]], 1);
    for (int i = tid; i < N_NODES * DIM / 4; i += stride) {
        float4 v = x4[i];
        ushort4 r;
        r.x = f2bf(v.x); r.y = f2bf(v.y); r.z = f2bf(v.z); r.w = f2bf(v.w);
        *(ushort4*)(xb + (size_t)i * 4) = r;
    }
    for (int i = tid; i < 3 * DIM * DIM; i += stride) {   // Wt[br][n][k] = W[br][k][n]
        int b = i >> 14, r2 = i & (DIM * DIM - 1);
        int k = r2 >> 7, n = r2 & 127;
        const float* W = (b == 0) ? We : (b == 1) ? W1 : W2;
        Wt[b * DIM * DIM + n * DIM + k] = f2bf(W[r2]);
    }
    for (int i = tid; i < 384 * OUTD; i += stride) {      // Wct[o][k] = Wc[k][o]
        int k = i >> 4, o = i & 15;
        Wct[o * 384 + k] = f2bf(Wc[i]);
    }
}

// ---------------- scans (build CSR offsets) ----------------
__global__ void k_scan1(const int* __restrict__ deg, int* __restrict__ bsum) {
    __shared__ int sd[256];
    int t = threadIdx.x;
    int base = blockIdx.x * SCAN_CHUNK + t * 4;
    int s = 0;
#pragma unroll
    for (int j = 0; j < 4; ++j) { int i = base + j; if (i < N_NODES) s += deg[i]; }
    sd[t] = s;
    __syncthreads();
    for (int off = 128; off > 0; off >>= 1) {
        if (t < off) sd[t] += sd[t + off];
        __syncthreads();
    }
    if (t == 0) bsum[blockIdx.x] = sd[0];
}

__global__ void k_scan2(const int* __restrict__ bsum, int* __restrict__ boff,
                        int* __restrict__ offsets) {
    __shared__ int s[128];
    int t = threadIdx.x;
    int v = (t < NB) ? bsum[t] : 0;
    s[t] = v;
    __syncthreads();
    for (int off = 1; off < 128; off <<= 1) {
        int a = (t >= off) ? s[t - off] : 0;
        __syncthreads();
        s[t] += a;
        __syncthreads();
    }
    if (t < NB) boff[t] = s[t] - v;
    if (t == NB - 1) offsets[N_NODES] = s[t];
}

__global__ void k_scan3(const int* __restrict__ deg, const int* __restrict__ boff,
                        int* __restrict__ offsets, int* __restrict__ cursor) {
    __shared__ int sd[256];
    int t = threadIdx.x;
    int base = blockIdx.x * SCAN_CHUNK + t * 4;
    int d[4];
    int s = 0;
#pragma unroll
    for (int j = 0; j < 4; ++j) {
        int i = base + j;
        d[j] = (i < N_NODES) ? deg[i] : 0;
        s += d[j];
    }
    sd[t] = s;
    __syncthreads();
    for (int off = 1; off < 256; off <<= 1) {
        int add = (t >= off) ? sd[t - off] : 0;
        __syncthreads();
        sd[t] += add;
        __syncthreads();
    }
    int run = boff[blockIdx.x] + (sd[t] - s);
#pragma unroll
    for (int j = 0; j < 4; ++j) {
        int i = base + j;
        if (i < N_NODES) { offsets[i] = run; cursor[i] = run; run += d[j]; }
    }
}

// ---------------- scatter, destination-sliced so writes stay in one XCD's L2 ----------
#define SLICES 8
#define RPS (N_NODES / SLICES)   // 12500 rows/slice -> 50 KB csr window
#define SBPS 224                 // blocks per slice

__global__ __launch_bounds__(256) void k_scatter(const int* __restrict__ row,
                                                 const int* __restrict__ col,
                                                 int* __restrict__ cursor,
                                                 int* __restrict__ csr_col) {
    int slice = blockIdx.x % SLICES;      // XCD round-robin (perf heuristic only)
    int bi    = blockIdx.x / SLICES;
    int lo = slice * RPS, hi = lo + RPS;
    int stride = SBPS * 256;
    for (int e = bi * 256 + threadIdx.x; e < N_EDGES; e += stride) {
        int r = row[e];
        int c = col[e];
        if (r >= lo && r < hi) {
            int p = atomicAdd(&cursor[r], 1);
            csr_col[p] = c;
        }
    }
}

// ---------------- SpMM (bf16 gather, fp32 accum), one wave per node ----------------
// MODE 1: out_n = sum * dinv;  out_r = raw sum (for 2-hop: y1*deg == raw sum)
// MODE 2: out_n = sum * dinv^2 (input is raw 1-hop sums)
template <int MODE>
__global__ __launch_bounds__(256) void k_spmm(const ushort* __restrict__ in,
                                              ushort* __restrict__ out_n,
                                              ushort* __restrict__ out_r,
                                              const int* __restrict__ offsets,
                                              const int* __restrict__ csr_col,
                                              const int* __restrict__ deg) {
    int wid = threadIdx.x >> 6, lane = threadIdx.x & 63;
    int node = blockIdx.x * 4 + wid;
    int start = __builtin_amdgcn_readfirstlane(offsets[node]);
    int end   = __builtin_amdgcn_readfirstlane(offsets[node + 1]);
    float a0 = 0.f, a1 = 0.f, b0 = 0.f, b1 = 0.f;
    int j = start;
    for (; j + 8 <= end; j += 8) {
        int c0 = csr_col[j + 0], c1 = csr_col[j + 1];
        int c2 = csr_col[j + 2], c3 = csr_col[j + 3];
        int c4 = csr_col[j + 4], c5 = csr_col[j + 5];
        int c6 = csr_col[j + 6], c7 = csr_col[j + 7];
        uint v0 = *(const uint*)(in + ((size_t)c0 << 7) + lane * 2);
        uint v1 = *(const uint*)(in + ((size_t)c1 << 7) + lane * 2);
        uint v2 = *(const uint*)(in + ((size_t)c2 << 7) + lane * 2);
        uint v3 = *(const uint*)(in + ((size_t)c3 << 7) + lane * 2);
        uint v4 = *(const uint*)(in + ((size_t)c4 << 7) + lane * 2);
        uint v5 = *(const uint*)(in + ((size_t)c5 << 7) + lane * 2);
        uint v6 = *(const uint*)(in + ((size_t)c6 << 7) + lane * 2);
        uint v7 = *(const uint*)(in + ((size_t)c7 << 7) + lane * 2);
        a0 += bflo(v0) + bflo(v1) + bflo(v2) + bflo(v3);
        a1 += bfhi(v0) + bfhi(v1) + bfhi(v2) + bfhi(v3);
        b0 += bflo(v4) + bflo(v5) + bflo(v6) + bflo(v7);
        b1 += bfhi(v4) + bfhi(v5) + bfhi(v6) + bfhi(v7);
    }
    for (; j < end; ++j) {
        int c = csr_col[j];
        uint v = *(const uint*)(in + ((size_t)c << 7) + lane * 2);
        a0 += bflo(v);
        a1 += bfhi(v);
    }
    a0 += b0; a1 += b1;
    float dv = 1.f / (float)max(deg[node], 1);
    if (MODE == 1) {
        uint r = (uint)f2bf(a0) | ((uint)f2bf(a1) << 16);
        *(uint*)(out_r + ((size_t)node << 7) + lane * 2) = r;
        uint o = (uint)f2bf(a0 * dv) | ((uint)f2bf(a1 * dv) << 16);
        *(uint*)(out_n + ((size_t)node << 7) + lane * 2) = o;
    } else {
        float sc = dv * dv;
        uint o = (uint)f2bf(a0 * sc) | ((uint)f2bf(a1 * sc) << 16);
        *(uint*)(out_n + ((size_t)node << 7) + lane * 2) = o;
    }
}

// ---------------- fused MFMA GEMM x3 + relu + classifier ----------------
#define XSS (DIM + 8)   // 136 bf16 = 272B row stride

__global__ __launch_bounds__(256) void k_fused(
        const ushort* __restrict__ xb, const ushort* __restrict__ y1b,
        const ushort* __restrict__ y2b,
        const ushort* __restrict__ Wt, const ushort* __restrict__ Wct,
        const float* __restrict__ b_ego, const float* __restrict__ b_h1,
        const float* __restrict__ b_h2, const float* __restrict__ b_cls,
        float* __restrict__ out) {
    __shared__ __align__(16) ushort Xs[32 * XSS];
    __shared__ __align__(16) ushort Hs[32 * XSS];

    int t = threadIdx.x;
    int lane = t & 63, w = t >> 6;
    int q = lane >> 4, l = lane & 15;
    int node0 = blockIdx.x * 32;

    f32x4 cout0 = {0.f, 0.f, 0.f, 0.f}, cout1 = {0.f, 0.f, 0.f, 0.f};

    for (int br = 0; br < 3; ++br) {
        const ushort* src = (br == 0) ? xb : (br == 1) ? y1b : y2b;
        const ushort* Wtb = Wt + br * DIM * DIM;
        const float* bias = (br == 0) ? b_ego : (br == 1) ? b_h1 : b_h2;

        __syncthreads();
        {   // stage 32x128 bf16 tile
            int row = t >> 3, col = (t & 7) * 16;
            const ushort* sp = src + ((size_t)(node0 + row) << 7) + col;
            uint4 u0 = *(const uint4*)sp;
            uint4 u1 = *(const uint4*)(sp + 8);
            *(uint4*)(Xs + row * XSS + col) = u0;
            *(uint4*)(Xs + row * XSS + col + 8) = u1;
        }
        __syncthreads();

        short8 afr[2][4];
#pragma unroll
        for (int mt = 0; mt < 2; ++mt)
#pragma unroll
            for (int ks = 0; ks < 4; ++ks)
                afr[mt][ks] = *(const short8*)(Xs + (mt * 16 + l) * XSS + ks * 32 + q * 8);
        short8 bfr[2][4];
#pragma unroll
        for (int nt = 0; nt < 2; ++nt)
#pragma unroll
            for (int ks = 0; ks < 4; ++ks)
                bfr[nt][ks] = *(const short8*)(Wtb + (size_t)(w * 32 + nt * 16 + l) * DIM + ks * 32 + q * 8);

        f32x4 hc[2][2];
        hc[0][0] = hc[0][1] = hc[1][0] = hc[1][1] = (f32x4){0.f, 0.f, 0.f, 0.f};
#pragma unroll
        for (int ks = 0; ks < 4; ++ks)
#pragma unroll
            for (int mt = 0; mt < 2; ++mt)
#pragma unroll
                for (int nt = 0; nt < 2; ++nt)
                    hc[mt][nt] = __builtin_amdgcn_mfma_f32_16x16x32_bf16(
                        afr[mt][ks], bfr[nt][ks], hc[mt][nt], 0, 0, 0);

#pragma unroll
        for (int nt = 0; nt < 2; ++nt) {
            float bv = bias[w * 32 + nt * 16 + l];
#pragma unroll
            for (int mt = 0; mt < 2; ++mt)
#pragma unroll
                for (int r = 0; r < 4; ++r) {
                    float v = hc[mt][nt][r] + bv;
                    v = v > 0.f ? v : 0.f;
                    Hs[(mt * 16 + q * 4 + r) * XSS + w * 32 + nt * 16 + l] = f2bf(v);
                }
        }
        __syncthreads();

        short8 ha0 = *(const short8*)(Hs + l * XSS + w * 32 + q * 8);
        short8 ha1 = *(const short8*)(Hs + (16 + l) * XSS + w * 32 + q * 8);
        short8 wc  = *(const short8*)(Wct + (size_t)l * 384 + br * DIM + w * 32 + q * 8);
        cout0 = __builtin_amdgcn_mfma_f32_16x16x32_bf16(ha0, wc, cout0, 0, 0, 0);
        cout1 = __builtin_amdgcn_mfma_f32_16x16x32_bf16(ha1, wc, cout1, 0, 0, 0);
    }

    float* red = (float*)Xs;
#pragma unroll
    for (int r = 0; r < 4; ++r) {
        red[w * 512 + (q * 4 + r) * 16 + l]      = cout0[r];
        red[w * 512 + (16 + q * 4 + r) * 16 + l] = cout1[r];
    }
    __syncthreads();
#pragma unroll
    for (int p = t; p < 512; p += 256) {
        float s = red[p] + red[512 + p] + red[1024 + p] + red[1536 + p];
        out[(size_t)node0 * OUTD + p] = s + b_cls[p & 15];
    }
}

// ---------------- launcher ----------------
static inline size_t align256(size_t v) { return (v + 255) & ~(size_t)255; }

extern "C" void kernel_launch(void* const* d_in, const int* in_sizes, int n_in,
                              void* d_out, int out_size, void* d_ws, size_t ws_size,
                              hipStream_t stream) {
    const float* x      = (const float*)d_in[0];
    const int*   ei     = (const int*)d_in[1];
    const float* W_ego  = (const float*)d_in[2];
    const float* b_ego  = (const float*)d_in[3];
    const float* W_h1   = (const float*)d_in[4];
    const float* b_h1   = (const float*)d_in[5];
    const float* W_h2   = (const float*)d_in[6];
    const float* b_h2   = (const float*)d_in[7];
    const float* W_cls  = (const float*)d_in[8];
    const float* b_cls  = (const float*)d_in[9];
    float* out = (float*)d_out;

    const int* row = ei;
    const int* col = ei + N_EDGES;

    char* p = (char*)d_ws;
    int* deg      = (int*)p;    p += align256((size_t)N_NODES * 4);
    int* offsets  = (int*)p;    p += align256((size_t)(N_NODES + 1) * 4);
    int* cursor   = (int*)p;    p += align256((size_t)N_NODES * 4);
    int* bsum     = (int*)p;    p += align256((size_t)NB * 4);
    int* boff     = (int*)p;    p += align256((size_t)NB * 4);
    int* csr_col  = (int*)p;    p += align256((size_t)N_EDGES * 4);
    ushort* xb    = (ushort*)p; p += align256((size_t)N_NODES * DIM * 2);
    ushort* y1b   = (ushort*)p; p += align256((size_t)N_NODES * DIM * 2);
    ushort* y1r   = (ushort*)p; p += align256((size_t)N_NODES * DIM * 2);
    ushort* y2b   = (ushort*)p; p += align256((size_t)N_NODES * DIM * 2);
    ushort* Wt    = (ushort*)p; p += align256((size_t)3 * DIM * DIM * 2);
    ushort* Wct   = (ushort*)p; p += align256((size_t)384 * OUTD * 2);

    hipMemsetAsync(deg, 0, (size_t)N_NODES * 4, stream);

    k_prep<<<2048, 256, 0, stream>>>((const float4*)x, row, W_ego, W_h1, W_h2, W_cls,
                                     xb, Wt, Wct, deg);
    k_scan1<<<NB, 256, 0, stream>>>(deg, bsum);
    k_scan2<<<1, 128, 0, stream>>>(bsum, boff, offsets);
    k_scan3<<<NB, 256, 0, stream>>>(deg, boff, offsets, cursor);
    k_scatter<<<SLICES * SBPS, 256, 0, stream>>>(row, col, cursor, csr_col);

    k_spmm<1><<<N_NODES / 4, 256, 0, stream>>>(xb,  y1b, y1r, offsets, csr_col, deg);
    k_spmm<2><<<N_NODES / 4, 256, 0, stream>>>(y1r, y2b, nullptr, offsets, csr_col, deg);

    k_fused<<<N_NODES / 32, 256, 0, stream>>>(xb, y1b, y2b, Wt, Wct,
                                              b_ego, b_h1, b_h2, b_cls, out);
}